// Round 7
// baseline (214.859 us; speedup 1.0000x reference)
//
#include <hip/hip_runtime.h>

// ---------- types / helpers ----------
typedef __attribute__((ext_vector_type(8))) short short8;   // 8 x bf16 (raw)
typedef __attribute__((ext_vector_type(4))) short short4v;  // 4 x bf16 (raw)
typedef __attribute__((ext_vector_type(4))) float f32x4;

#if __has_builtin(__builtin_amdgcn_exp2f)
#define EXP2F(x) __builtin_amdgcn_exp2f(x)
#define QSCALE 0.1803368801111601f   /* log2(e)/8 : logits in log2 domain */
#else
#define EXP2F(x) __expf(x)
#define QSCALE 0.125f                /* logits in ln domain */
#endif

__device__ __forceinline__ short f2bf(float f) {
  unsigned u = __builtin_bit_cast(unsigned, f);
  u += 0x7fffu + ((u >> 16) & 1u);           // RNE
  return (short)(u >> 16);
}
__device__ __forceinline__ float bf2f(short s) {
  unsigned u = ((unsigned)(unsigned short)s) << 16;
  return __builtin_bit_cast(float, u);
}
__device__ __forceinline__ void async_load16(const short* g, short* l) {
  __builtin_amdgcn_global_load_lds(
      (const __attribute__((address_space(1))) unsigned int*)g,
      (__attribute__((address_space(3))) unsigned int*)l, 16, 0, 0);
}

// ---------- fused pre-pass: blocks 0..4095 convert x; 4096..8191 transpose weights ----------
// One dispatch instead of two (launch-overhead reduction; ~10us/dispatch in graph replay).
__global__ __launch_bounds__(256) void fused_pre(
    const float* __restrict__ x, short* __restrict__ xb,
    const float* __restrict__ W0, const float* __restrict__ W1,
    const float* __restrict__ W2, const float* __restrict__ W3,
    short* __restrict__ T0, short* __restrict__ T1,
    short* __restrict__ T2, short* __restrict__ T3) {
  __shared__ float tile[32][33];
  if (blockIdx.x < 4096) {
    int i = (blockIdx.x * 256 + threadIdx.x) * 4;
    float4 v = *(const float4*)(x + i);
    short4v o;
    o[0] = f2bf(v.x); o[1] = f2bf(v.y); o[2] = f2bf(v.z); o[3] = f2bf(v.w);
    *(short4v*)(xb + i) = o;
    return;
  }
  int bid = blockIdx.x - 4096;        // 0..4095
  int z = bid >> 10;                  // weight index
  int by = (bid >> 5) & 31, bx = bid & 31;
  const float* W; short* T;
  switch (z) {
    case 0: W = W0; T = T0; break;
    case 1: W = W1; T = T1; break;
    case 2: W = W2; T = T2; break;
    default: W = W3; T = T3; break;
  }
  int tx = threadIdx.x & 31, ty = threadIdx.x >> 5;
  int c = bx * 32 + tx;
  #pragma unroll
  for (int i = 0; i < 4; ++i) {
    int r = by * 32 + ty + i * 8;
    tile[ty + i * 8][tx] = W[(size_t)r * 1024 + c];
  }
  __syncthreads();
  int k = by * 32 + tx;
  #pragma unroll
  for (int i = 0; i < 4; ++i) {
    int n = bx * 32 + ty + i * 8;
    T[(size_t)n * 1024 + k] = f2bf(tile[tx][ty + i * 8]);
  }
}

// ---------- GEMM core, BK=64: C(128x128) += A @ Bt^T ----------
// LDS tiles 128x64 bf16 (16KB each). Row = 8 chunks of 16B; phys chunk = logical ^ (row&7).
__device__ __forceinline__ void gemm_core_128_bk64(
    const short* __restrict__ A, const short* __restrict__ Bt,
    int m0, int n0, short* As, short* Bs, f32x4 acc[4][4]) {
  const int tid = threadIdx.x;
  const int wave = tid >> 6, lane = tid & 63;
  const int wm = wave >> 1, wn = wave & 1;
  const int lr = lane & 15, quad = lane >> 4;
  const int l7 = lr & 7;
  const int r8 = lane >> 3, cb = lane & 7;
  const int src = (cb ^ r8) << 3;              // shorts: XOR-swizzled source chunk
  for (int k0 = 0; k0 < 1024; k0 += 64) {
    __syncthreads();
    #pragma unroll
    for (int jj = 0; jj < 4; ++jj) {
      int j = wave * 4 + jj;                   // waveload 0..15, 8 rows each
      int row = j * 8 + r8;
      async_load16(A + (size_t)(m0 + row) * 1024 + k0 + src, As + j * 512 + lane * 8);
      async_load16(Bt + (size_t)(n0 + row) * 1024 + k0 + src, Bs + j * 512 + lane * 8);
    }
    __syncthreads();
    #pragma unroll
    for (int c = 0; c < 2; ++c) {
      short8 af[4], bfr[4];
      #pragma unroll
      for (int i = 0; i < 4; ++i) {
        int ra = wm * 64 + i * 16 + lr;
        af[i] = *(const short8*)(As + ra * 64 + ((((c * 4 + quad) ^ l7)) << 3));
        int rb = wn * 64 + i * 16 + lr;
        bfr[i] = *(const short8*)(Bs + rb * 64 + ((((c * 4 + quad) ^ l7)) << 3));
      }
      #pragma unroll
      for (int i = 0; i < 4; ++i)
        #pragma unroll
        for (int j = 0; j < 4; ++j)
          acc[i][j] = __builtin_amdgcn_mfma_f32_16x16x32_bf16(af[i], bfr[j], acc[i][j], 0, 0, 0);
    }
  }
}

// ---------- fused QKV projection. which: 0=Q (prescaled), 1=K, 2=V (transposed per head) ----------
__global__ __launch_bounds__(256, 2) void qkv_gemm(
    const short* __restrict__ xb,
    const short* __restrict__ WqT, const short* __restrict__ WkT, const short* __restrict__ WvT,
    const float* __restrict__ bq, const float* __restrict__ bk, const float* __restrict__ bv,
    short* __restrict__ Qb, short* __restrict__ Kb, short* __restrict__ Vt) {
  __shared__ short As[128 * 64];
  __shared__ short Bs[128 * 64];
  int which = blockIdx.x >> 3;
  int n0 = (blockIdx.x & 7) * 128;
  int m0 = blockIdx.y * 128;
  const short* Bt = (which == 0) ? WqT : (which == 1) ? WkT : WvT;
  const float* bias = (which == 0) ? bq : (which == 1) ? bk : bv;
  f32x4 acc[4][4] = {};
  gemm_core_128_bk64(xb, Bt, m0, n0, As, Bs, acc);
  const int lane = threadIdx.x & 63, wave = threadIdx.x >> 6;
  const int wm = wave >> 1, wn = wave & 1;
  const int lr = lane & 15, quad = lane >> 4;
  if (which < 2) {
    short* Out = (which == 0) ? Qb : Kb;
    const float scale = (which == 0) ? QSCALE : 1.0f;
    #pragma unroll
    for (int i = 0; i < 4; ++i)
      #pragma unroll
      for (int j = 0; j < 4; ++j) {
        int col = n0 + wn * 64 + j * 16 + lr;
        float bb = bias[col];
        int rowb = m0 + wm * 64 + i * 16 + quad * 4;
        #pragma unroll
        for (int r = 0; r < 4; ++r)
          Out[(size_t)(rowb + r) * 1024 + col] = f2bf((acc[i][j][r] + bb) * scale);
      }
  } else {
    #pragma unroll
    for (int i = 0; i < 4; ++i)
      #pragma unroll
      for (int j = 0; j < 4; ++j) {
        int col = n0 + wn * 64 + j * 16 + lr;
        float bb = bias[col];
        int h = col >> 6, d = col & 63;
        int rowb = m0 + wm * 64 + i * 16 + quad * 4;
        int b = rowb >> 11, s = rowb & 2047;
        short4v pk;
        #pragma unroll
        for (int r = 0; r < 4; ++r) pk[r] = f2bf(acc[i][j][r] + bb);
        *(short4v*)(Vt + ((size_t)(b * 16 + h) * 64 + d) * 2048 + s) = pk;
      }
  }
}

// ---------- dsV[bh][d] = sum_s ds[b][s] * V[bh][d][s] — deterministic, no memset/atomics ----------
__global__ __launch_bounds__(256) void dsv_kernel(const short* __restrict__ Vt,
                                                  const float* __restrict__ ds,
                                                  float* __restrict__ dsV) {
  int bh = blockIdx.x;
  int b = bh >> 4;
  int tid = threadIdx.x;
  int d = tid >> 2, part = tid & 3;
  const short* vrow = Vt + ((size_t)bh * 64 + d) * 2048 + part * 512;
  const float* dsrow = ds + (size_t)b * 2048 + part * 512;
  float acc = 0.f;
  for (int i = 0; i < 512; i += 8) {
    short8 v = *(const short8*)(vrow + i);
    float4 f0 = *(const float4*)(dsrow + i);
    float4 f1 = *(const float4*)(dsrow + i + 4);
    acc += f0.x * bf2f(v[0]) + f0.y * bf2f(v[1]) + f0.z * bf2f(v[2]) + f0.w * bf2f(v[3]);
    acc += f1.x * bf2f(v[4]) + f1.y * bf2f(v[5]) + f1.z * bf2f(v[6]) + f1.w * bf2f(v[7]);
  }
  acc += __shfl_xor(acc, 1);
  acc += __shfl_xor(acc, 2);
  if (part == 0) dsV[bh * 64 + d] = acc;
}

// ---------- attention: R4 structure — 256-thr block, 4 waves = (qg x half) ----------
__global__ __launch_bounds__(256, 2) void attn_kernel(
    const short* __restrict__ Qb, const short* __restrict__ Kb,
    const short* __restrict__ Vt, const float* __restrict__ dsV,
    const float* __restrict__ beta_p, short* __restrict__ ctx) {
  __shared__ short smem[32768];  // 64 KB
  const int tid = threadIdx.x, wave = tid >> 6, lane = tid & 63;
  const int bh = blockIdx.x >> 4, qt = blockIdx.x & 15;
  const int b = bh >> 4, h = bh & 15;
  const size_t bS = (size_t)b * 2048;
  const int lr = lane & 15, quad = lane >> 4;
  const int qg = wave & 1, half = wave >> 1;
  const int q0 = qt * 128 + qg * 64;
  const int l7 = lr & 7;

  short* Ksh = smem + half * 8192;          // 64 keys x 64 dims
  short* Vsh = Ksh + 4096;                  // 64 dims x 64 keys
  short* myP = smem + 16384 + wave * 4096;  // 64 q x 64 keys, swizzled 8B slots

  short8 qf[4][2];
  #pragma unroll
  for (int mb = 0; mb < 4; ++mb)
    #pragma unroll
    for (int c = 0; c < 2; ++c)
      qf[mb][c] = *(const short8*)(Qb + (bS + q0 + mb * 16 + lr) * 1024 + h * 64 + c * 32 + quad * 8);

  f32x4 O[4][4] = {};              // O^T fragments: [mb][db], col=q, row=dim
  float lacc[4] = {0.f, 0.f, 0.f, 0.f};

  const int srow = lane >> 3;            // row within 8-row group
  const int scb = (lane & 7) ^ srow;     // source 16B chunk (XOR swizzle)

  for (int t = 0; t < 16; ++t) {
    const int k0 = (half * 16 + t) * 64;
    __syncthreads();
    if (qg == 0) {
      #pragma unroll
      for (int c = 0; c < 8; ++c) {
        int rk = c * 8 + srow;
        async_load16(Kb + (bS + k0 + rk) * 1024 + h * 64 + scb * 8, Ksh + c * 512);
      }
    } else {
      #pragma unroll
      for (int c = 0; c < 8; ++c) {
        int rv = c * 8 + srow;
        async_load16(Vt + ((size_t)bh * 64 + rv) * 2048 + k0 + scb * 8, Vsh + c * 512);
      }
    }
    __syncthreads();

    // S^T = K @ Q^T ; P = exp2(S^T) -> per-wave LDS [q][key], 8B-slot swizzle ^(2*l7)
    #pragma unroll
    for (int kb = 0; kb < 4; ++kb) {
      const short* kr = Ksh + (kb * 16 + lr) * 64;
      short8 kf0 = *(const short8*)(kr + ((quad ^ l7) << 3));
      short8 kf1 = *(const short8*)(kr + (((4 + quad) ^ l7) << 3));
      #pragma unroll
      for (int mb = 0; mb < 4; ++mb) {
        f32x4 st = {0.f, 0.f, 0.f, 0.f};
        st = __builtin_amdgcn_mfma_f32_16x16x32_bf16(kf0, qf[mb][0], st, 0, 0, 0);
        st = __builtin_amdgcn_mfma_f32_16x16x32_bf16(kf1, qf[mb][1], st, 0, 0, 0);
        float p0 = EXP2F(st[0]), p1 = EXP2F(st[1]);
        float p2 = EXP2F(st[2]), p3 = EXP2F(st[3]);
        lacc[mb] += (p0 + p1) + (p2 + p3);
        unsigned a0 = __builtin_bit_cast(unsigned, p0) + 0x8000u;
        unsigned a1 = __builtin_bit_cast(unsigned, p1) + 0x8000u;
        unsigned a2 = __builtin_bit_cast(unsigned, p2) + 0x8000u;
        unsigned a3 = __builtin_bit_cast(unsigned, p3) + 0x8000u;
        uint2 pk;
        pk.x = __builtin_amdgcn_perm(a1, a0, 0x07060302u);
        pk.y = __builtin_amdgcn_perm(a3, a2, 0x07060302u);
        int phys = (4 * kb + quad) ^ (2 * l7);         // 8B slot
        *(uint2*)(myP + (mb * 16 + lr) * 64 + phys * 4) = pk;
      }
    }
    // O^T += V^T @ P^T
    #pragma unroll
    for (int kc = 0; kc < 2; ++kc) {
      short8 pf[4];
      #pragma unroll
      for (int mb = 0; mb < 4; ++mb) {
        int phys = (8 * kc + 2 * quad) ^ (2 * l7);     // even 8B slot, pair contiguous
        pf[mb] = *(const short8*)(myP + (mb * 16 + lr) * 64 + phys * 4);
      }
      #pragma unroll
      for (int db = 0; db < 4; ++db) {
        const short* vr = Vsh + (db * 16 + lr) * 64;
        short8 vf = *(const short8*)(vr + (((kc * 4 + quad) ^ l7) << 3));
        #pragma unroll
        for (int mb = 0; mb < 4; ++mb)
          O[mb][db] = __builtin_amdgcn_mfma_f32_16x16x32_bf16(vf, pf[mb], O[mb][db], 0, 0, 0);
      }
    }
  }

  // ---- merge the two key-halves through LDS ----
  float* Obuf = (float*)smem;                 // 8192 floats (32 KB) over Ks/Vs region
  float* lbuf = (float*)(smem + 16384);       // 512 floats over P region
  const int qs = (quad + lr) & 3;             // bank swizzle for Obuf
  __syncthreads();
  if (half == 1) {
    #pragma unroll
    for (int mb = 0; mb < 4; ++mb) {
      #pragma unroll
      for (int db = 0; db < 4; ++db)
        *(f32x4*)(Obuf + ((qg * 4 + mb) * 4 + db) * 256 + lr * 16 + qs * 4) = O[mb][db];
      lbuf[(qg * 4 + mb) * 64 + quad * 16 + lr] = lacc[mb];
    }
  }
  __syncthreads();
  if (half == 0) {
    float beta = *beta_p;
    #pragma unroll
    for (int mb = 0; mb < 4; ++mb) {
      #pragma unroll
      for (int db = 0; db < 4; ++db)
        O[mb][db] += *(const f32x4*)(Obuf + ((qg * 4 + mb) * 4 + db) * 256 + lr * 16 + qs * 4);
      float v = lacc[mb] + lbuf[(qg * 4 + mb) * 64 + quad * 16 + lr];
      v += __shfl_xor(v, 16);
      v += __shfl_xor(v, 32);
      float linv = (1.f - beta) / v;
      #pragma unroll
      for (int db = 0; db < 4; ++db) {
        float4 dv = *(const float4*)(dsV + bh * 64 + db * 16 + quad * 4);
        short4v o;
        o[0] = f2bf(O[mb][db][0] * linv + beta * dv.x);
        o[1] = f2bf(O[mb][db][1] * linv + beta * dv.y);
        o[2] = f2bf(O[mb][db][2] * linv + beta * dv.z);
        o[3] = f2bf(O[mb][db][3] * linv + beta * dv.w);
        *(short4v*)(ctx + (bS + q0 + mb * 16 + lr) * 1024 + h * 64 + db * 16 + quad * 4) = o;
      }
    }
  }
}

// ---------- output projection, BK=64: 64(M) x 128(N) tiles -> 512 blocks ----------
__global__ __launch_bounds__(256, 2) void out_gemm(
    const short* __restrict__ ctx, const short* __restrict__ WoT,
    const float* __restrict__ bo, float* __restrict__ out) {
  __shared__ short As[64 * 64];    // 8 KB
  __shared__ short Bs[128 * 64];   // 16 KB
  const int n0 = blockIdx.x * 128, m0 = blockIdx.y * 64;
  const int tid = threadIdx.x, wave = tid >> 6, lane = tid & 63;
  const int wm = wave >> 1, wn = wave & 1;
  const int lr = lane & 15, quad = lane >> 4;
  const int l7 = lr & 7;
  const int r8 = lane >> 3, cb = lane & 7;
  const int src = (cb ^ r8) << 3;
  f32x4 acc[2][4] = {};
  for (int k0 = 0; k0 < 1024; k0 += 64) {
    __syncthreads();
    #pragma unroll
    for (int jj = 0; jj < 2; ++jj) {
      int j = wave * 2 + jj;
      int row = j * 8 + r8;
      async_load16(ctx + (size_t)(m0 + row) * 1024 + k0 + src, As + j * 512 + lane * 8);
    }
    #pragma unroll
    for (int jj = 0; jj < 4; ++jj) {
      int j = wave * 4 + jj;
      int row = j * 8 + r8;
      async_load16(WoT + (size_t)(n0 + row) * 1024 + k0 + src, Bs + j * 512 + lane * 8);
    }
    __syncthreads();
    #pragma unroll
    for (int c = 0; c < 2; ++c) {
      short8 af[2], bfr[4];
      #pragma unroll
      for (int i = 0; i < 2; ++i) {
        int ra = wm * 32 + i * 16 + lr;
        af[i] = *(const short8*)(As + ra * 64 + (((c * 4 + quad) ^ l7) << 3));
      }
      #pragma unroll
      for (int j = 0; j < 4; ++j) {
        int rb = wn * 64 + j * 16 + lr;
        bfr[j] = *(const short8*)(Bs + rb * 64 + (((c * 4 + quad) ^ l7) << 3));
      }
      #pragma unroll
      for (int i = 0; i < 2; ++i)
        #pragma unroll
        for (int j = 0; j < 4; ++j)
          acc[i][j] = __builtin_amdgcn_mfma_f32_16x16x32_bf16(af[i], bfr[j], acc[i][j], 0, 0, 0);
    }
  }
  #pragma unroll
  for (int i = 0; i < 2; ++i)
    #pragma unroll
    for (int j = 0; j < 4; ++j) {
      int col = n0 + wn * 64 + j * 16 + lr;
      float bb = bo[col];
      int rowb = m0 + wm * 32 + i * 16 + quad * 4;
      #pragma unroll
      for (int r = 0; r < 4; ++r)
        out[(size_t)(rowb + r) * 1024 + col] = acc[i][j][r] + bb;
    }
}

// ---------- launcher: 5 dispatches (was 8) ----------
extern "C" void kernel_launch(void* const* d_in, const int* in_sizes, int n_in,
                              void* d_out, int out_size, void* d_ws, size_t ws_size,
                              hipStream_t stream) {
  const float* x    = (const float*)d_in[0];
  const float* dsc  = (const float*)d_in[1];
  const float* Wq   = (const float*)d_in[2];
  const float* bq   = (const float*)d_in[3];
  const float* Wk   = (const float*)d_in[4];
  const float* bk   = (const float*)d_in[5];
  const float* Wv   = (const float*)d_in[6];
  const float* bv   = (const float*)d_in[7];
  const float* Wo   = (const float*)d_in[8];
  const float* bo   = (const float*)d_in[9];
  const float* beta = (const float*)d_in[10];

  char* ws = (char*)d_ws;
  const size_t MB = 1u << 20;
  short* xb  = (short*)(ws + 0 * MB);    // 8 MB; reused as ctx after qkv_gemm
  short* WqT = (short*)(ws + 8 * MB);
  short* WkT = (short*)(ws + 10 * MB);
  short* WvT = (short*)(ws + 12 * MB);
  short* WoT = (short*)(ws + 14 * MB);
  short* Qb  = (short*)(ws + 16 * MB);
  short* Kb  = (short*)(ws + 24 * MB);
  short* Vt  = (short*)(ws + 32 * MB);
  float* dsV = (float*)(ws + 40 * MB);   // 8 KB
  short* ctx = xb;

  fused_pre<<<8192, 256, 0, stream>>>(x, xb, Wq, Wk, Wv, Wo, WqT, WkT, WvT, WoT);
  qkv_gemm<<<dim3(24, 32), 256, 0, stream>>>(xb, WqT, WkT, WvT, bq, bk, bv, Qb, Kb, Vt);
  dsv_kernel<<<32, 256, 0, stream>>>(Vt, dsc, dsV);
  attn_kernel<<<512, 256, 0, stream>>>(Qb, Kb, Vt, dsV, beta, ctx);
  out_gemm<<<dim3(8, 64), 256, 0, stream>>>(ctx, WoT, bo, (float*)d_out);
}

// Round 8
// 201.310 us; speedup vs baseline: 1.0673x; 1.0673x over previous
//
#include <hip/hip_runtime.h>

// ---------- types / helpers ----------
typedef __attribute__((ext_vector_type(8))) short short8;   // 8 x bf16 (raw)
typedef __attribute__((ext_vector_type(4))) short short4v;  // 4 x bf16 (raw)
typedef __attribute__((ext_vector_type(4))) float f32x4;

#if __has_builtin(__builtin_amdgcn_exp2f)
#define EXP2F(x) __builtin_amdgcn_exp2f(x)
#define QSCALE 0.1803368801111601f   /* log2(e)/8 : logits in log2 domain */
#else
#define EXP2F(x) __expf(x)
#define QSCALE 0.125f                /* logits in ln domain */
#endif

__device__ __forceinline__ short f2bf(float f) {
  unsigned u = __builtin_bit_cast(unsigned, f);
  u += 0x7fffu + ((u >> 16) & 1u);           // RNE
  return (short)(u >> 16);
}
__device__ __forceinline__ float bf2f(short s) {
  unsigned u = ((unsigned)(unsigned short)s) << 16;
  return __builtin_bit_cast(float, u);
}
__device__ __forceinline__ void async_load16(const short* g, short* l) {
  __builtin_amdgcn_global_load_lds(
      (const __attribute__((address_space(1))) unsigned int*)g,
      (__attribute__((address_space(3))) unsigned int*)l, 16, 0, 0);
}

// ---------- fused pre-pass ----------
// blocks 0..4095: convert x; 4096..8191: transpose weights; 8192: zero dsV
__global__ __launch_bounds__(256) void fused_pre(
    const float* __restrict__ x, short* __restrict__ xb,
    const float* __restrict__ W0, const float* __restrict__ W1,
    const float* __restrict__ W2, const float* __restrict__ W3,
    short* __restrict__ T0, short* __restrict__ T1,
    short* __restrict__ T2, short* __restrict__ T3,
    float* __restrict__ dsV) {
  __shared__ float tile[32][33];
  if (blockIdx.x < 4096) {
    int i = (blockIdx.x * 256 + threadIdx.x) * 4;
    float4 v = *(const float4*)(x + i);
    short4v o;
    o[0] = f2bf(v.x); o[1] = f2bf(v.y); o[2] = f2bf(v.z); o[3] = f2bf(v.w);
    *(short4v*)(xb + i) = o;
    return;
  }
  if (blockIdx.x == 8192) {   // zero dsV (2048 floats)
    float4 z = {0.f, 0.f, 0.f, 0.f};
    ((float4*)dsV)[threadIdx.x * 2] = z;
    ((float4*)dsV)[threadIdx.x * 2 + 1] = z;
    return;
  }
  int bid = blockIdx.x - 4096;        // 0..4095
  int z = bid >> 10;                  // weight index
  int by = (bid >> 5) & 31, bx = bid & 31;
  const float* W; short* T;
  switch (z) {
    case 0: W = W0; T = T0; break;
    case 1: W = W1; T = T1; break;
    case 2: W = W2; T = T2; break;
    default: W = W3; T = T3; break;
  }
  int tx = threadIdx.x & 31, ty = threadIdx.x >> 5;
  int c = bx * 32 + tx;
  #pragma unroll
  for (int i = 0; i < 4; ++i) {
    int r = by * 32 + ty + i * 8;
    tile[ty + i * 8][tx] = W[(size_t)r * 1024 + c];
  }
  __syncthreads();
  int k = by * 32 + tx;
  #pragma unroll
  for (int i = 0; i < 4; ++i) {
    int n = bx * 32 + ty + i * 8;
    T[(size_t)n * 1024 + k] = f2bf(tile[tx][ty + i * 8]);
  }
}

// ---------- GEMM core, BK=64: C(128x128) += A @ Bt^T ----------
__device__ __forceinline__ void gemm_core_128_bk64(
    const short* __restrict__ A, const short* __restrict__ Bt,
    int m0, int n0, short* As, short* Bs, f32x4 acc[4][4]) {
  const int tid = threadIdx.x;
  const int wave = tid >> 6, lane = tid & 63;
  const int wm = wave >> 1, wn = wave & 1;
  const int lr = lane & 15, quad = lane >> 4;
  const int l7 = lr & 7;
  const int r8 = lane >> 3, cb = lane & 7;
  const int src = (cb ^ r8) << 3;              // shorts: XOR-swizzled source chunk
  for (int k0 = 0; k0 < 1024; k0 += 64) {
    __syncthreads();
    #pragma unroll
    for (int jj = 0; jj < 4; ++jj) {
      int j = wave * 4 + jj;                   // waveload 0..15, 8 rows each
      int row = j * 8 + r8;
      async_load16(A + (size_t)(m0 + row) * 1024 + k0 + src, As + j * 512 + lane * 8);
      async_load16(Bt + (size_t)(n0 + row) * 1024 + k0 + src, Bs + j * 512 + lane * 8);
    }
    __syncthreads();
    #pragma unroll
    for (int c = 0; c < 2; ++c) {
      short8 af[4], bfr[4];
      #pragma unroll
      for (int i = 0; i < 4; ++i) {
        int ra = wm * 64 + i * 16 + lr;
        af[i] = *(const short8*)(As + ra * 64 + ((((c * 4 + quad) ^ l7)) << 3));
        int rb = wn * 64 + i * 16 + lr;
        bfr[i] = *(const short8*)(Bs + rb * 64 + ((((c * 4 + quad) ^ l7)) << 3));
      }
      #pragma unroll
      for (int i = 0; i < 4; ++i)
        #pragma unroll
        for (int j = 0; j < 4; ++j)
          acc[i][j] = __builtin_amdgcn_mfma_f32_16x16x32_bf16(af[i], bfr[j], acc[i][j], 0, 0, 0);
    }
  }
}

// ---------- fused QKV projection. 3 blocks/CU co-residency (768 blocks = 1 round) ----------
__global__ __launch_bounds__(256, 3) void qkv_gemm(
    const short* __restrict__ xb,
    const short* __restrict__ WqT, const short* __restrict__ WkT, const short* __restrict__ WvT,
    const float* __restrict__ bq, const float* __restrict__ bk, const float* __restrict__ bv,
    short* __restrict__ Qb, short* __restrict__ Kb, short* __restrict__ Vt) {
  __shared__ short As[128 * 64];
  __shared__ short Bs[128 * 64];
  int which = blockIdx.x >> 3;
  int n0 = (blockIdx.x & 7) * 128;
  int m0 = blockIdx.y * 128;
  const short* Bt = (which == 0) ? WqT : (which == 1) ? WkT : WvT;
  const float* bias = (which == 0) ? bq : (which == 1) ? bk : bv;
  f32x4 acc[4][4] = {};
  gemm_core_128_bk64(xb, Bt, m0, n0, As, Bs, acc);
  const int lane = threadIdx.x & 63, wave = threadIdx.x >> 6;
  const int wm = wave >> 1, wn = wave & 1;
  const int lr = lane & 15, quad = lane >> 4;
  if (which < 2) {
    short* Out = (which == 0) ? Qb : Kb;
    const float scale = (which == 0) ? QSCALE : 1.0f;
    #pragma unroll
    for (int i = 0; i < 4; ++i)
      #pragma unroll
      for (int j = 0; j < 4; ++j) {
        int col = n0 + wn * 64 + j * 16 + lr;
        float bb = bias[col];
        int rowb = m0 + wm * 64 + i * 16 + quad * 4;
        #pragma unroll
        for (int r = 0; r < 4; ++r)
          Out[(size_t)(rowb + r) * 1024 + col] = f2bf((acc[i][j][r] + bb) * scale);
      }
  } else {
    #pragma unroll
    for (int i = 0; i < 4; ++i)
      #pragma unroll
      for (int j = 0; j < 4; ++j) {
        int col = n0 + wn * 64 + j * 16 + lr;
        float bb = bias[col];
        int h = col >> 6, d = col & 63;
        int rowb = m0 + wm * 64 + i * 16 + quad * 4;
        int b = rowb >> 11, s = rowb & 2047;
        short4v pk;
        #pragma unroll
        for (int r = 0; r < 4; ++r) pk[r] = f2bf(acc[i][j][r] + bb);
        *(short4v*)(Vt + ((size_t)(b * 16 + h) * 64 + d) * 2048 + s) = pk;
      }
  }
}

// ---------- dsV[bh][d] = sum_s ds[b][s] * V[bh][d][s] ; parallel partials + atomics ----------
__global__ __launch_bounds__(256) void dsv_kernel(const short* __restrict__ Vt,
                                                  const float* __restrict__ ds,
                                                  float* __restrict__ dsV) {
  int bh = blockIdx.x, sc = blockIdx.y;
  int b = bh >> 4;
  int d = threadIdx.x >> 2, part = threadIdx.x & 3;
  const short* vrow = Vt + ((size_t)bh * 64 + d) * 2048 + sc * 256 + part * 64;
  const float* dsrow = ds + (size_t)b * 2048 + sc * 256 + part * 64;
  float acc = 0.f;
  #pragma unroll
  for (int i = 0; i < 64; i += 8) {
    short8 v = *(const short8*)(vrow + i);
    float4 f0 = *(const float4*)(dsrow + i);
    float4 f1 = *(const float4*)(dsrow + i + 4);
    acc += f0.x * bf2f(v[0]) + f0.y * bf2f(v[1]) + f0.z * bf2f(v[2]) + f0.w * bf2f(v[3]);
    acc += f1.x * bf2f(v[4]) + f1.y * bf2f(v[5]) + f1.z * bf2f(v[6]) + f1.w * bf2f(v[7]);
  }
  acc += __shfl_xor(acc, 1);
  acc += __shfl_xor(acc, 2);
  if (part == 0) atomicAdd(dsV + bh * 64 + d, acc);
}

// ---------- attention: double-buffered K/V, ONE barrier per tile ----------
// 256-thr block, wave = half*2 + qg; each wave 64 q x 1024 keys (16 tiles of 64).
// LDS 80KB: KV dbuf 2 x (2 halves x (K 8KB + V 8KB))/2 = 64KB, P 4 waves x 4KB = 16KB.
// Per tile: issue async stage(t+1) -> compute(t) -> __syncthreads (vmcnt drain
// overlaps compute). P round-trips in 32-key sub-tiles (in-wave, no barrier).
__global__ __launch_bounds__(256, 2) void attn_kernel(
    const short* __restrict__ Qb, const short* __restrict__ Kb,
    const short* __restrict__ Vt, const float* __restrict__ dsV,
    const float* __restrict__ beta_p, short* __restrict__ ctx) {
  __shared__ short smem[40960];  // 80 KB
  const int tid = threadIdx.x, wave = tid >> 6, lane = tid & 63;
  const int bh = blockIdx.x >> 4, qt = blockIdx.x & 15;
  const int b = bh >> 4, h = bh & 15;
  const size_t bS = (size_t)b * 2048;
  const int lr = lane & 15, quad = lane >> 4;
  const int qg = wave & 1, half = wave >> 1;
  const int q0 = qt * 128 + qg * 64;
  const int l7 = lr & 7;
  const int swz = 2 * (lr & 3);          // even P-slot swizzle (8 slots of 8B)

  short* myP = smem + 32768 + wave * 2048;   // 64q x 32k per wave

  const int srow = lane >> 3;
  const int scb = (lane & 7) ^ srow;     // XOR-swizzled source 16B chunk

  // Q B-frags: 64 q-rows x 64 dims (Q prescaled by log2(e)/8)
  short8 qf[4][2];
  #pragma unroll
  for (int mb = 0; mb < 4; ++mb)
    #pragma unroll
    for (int c = 0; c < 2; ++c)
      qf[mb][c] = *(const short8*)(Qb + (bS + q0 + mb * 16 + lr) * 1024 + h * 64 + c * 32 + quad * 8);

  f32x4 O[4][4] = {};
  float lacc[4] = {0.f, 0.f, 0.f, 0.f};

  // prologue: stage tile 0 into buffer 0
  {
    const int k0 = (half * 16) * 64;
    short* Ksh = smem + half * 8192;
    short* Vsh = Ksh + 4096;
    if (qg == 0) {
      #pragma unroll
      for (int c = 0; c < 8; ++c)
        async_load16(Kb + (bS + k0 + c * 8 + srow) * 1024 + h * 64 + scb * 8, Ksh + c * 512);
    } else {
      #pragma unroll
      for (int c = 0; c < 8; ++c)
        async_load16(Vt + ((size_t)bh * 64 + c * 8 + srow) * 2048 + k0 + scb * 8, Vsh + c * 512);
    }
  }
  __syncthreads();

  for (int t = 0; t < 16; ++t) {
    const int cur = t & 1;
    short* Ksh = smem + cur * 16384 + half * 8192;
    short* Vsh = Ksh + 4096;
    // issue next tile's staging (no wait) — drain overlaps the compute below
    if (t < 15) {
      const int k0n = (half * 16 + t + 1) * 64;
      short* Kn = smem + (cur ^ 1) * 16384 + half * 8192;
      short* Vn = Kn + 4096;
      if (qg == 0) {
        #pragma unroll
        for (int c = 0; c < 8; ++c)
          async_load16(Kb + (bS + k0n + c * 8 + srow) * 1024 + h * 64 + scb * 8, Kn + c * 512);
      } else {
        #pragma unroll
        for (int c = 0; c < 8; ++c)
          async_load16(Vt + ((size_t)bh * 64 + c * 8 + srow) * 2048 + k0n + scb * 8, Vn + c * 512);
      }
    }
    // compute tile t: two 32-key halves, P round-trip per half (in-wave)
    #pragma unroll
    for (int kc = 0; kc < 2; ++kc) {
      #pragma unroll
      for (int kbl = 0; kbl < 2; ++kbl) {
        int kb = kc * 2 + kbl;
        const short* kr = Ksh + (kb * 16 + lr) * 64;
        short8 kf0 = *(const short8*)(kr + ((quad ^ l7) << 3));
        short8 kf1 = *(const short8*)(kr + (((4 + quad) ^ l7) << 3));
        #pragma unroll
        for (int mb = 0; mb < 4; ++mb) {
          f32x4 st = {0.f, 0.f, 0.f, 0.f};
          st = __builtin_amdgcn_mfma_f32_16x16x32_bf16(kf0, qf[mb][0], st, 0, 0, 0);
          st = __builtin_amdgcn_mfma_f32_16x16x32_bf16(kf1, qf[mb][1], st, 0, 0, 0);
          float p0 = EXP2F(st[0]), p1 = EXP2F(st[1]);
          float p2 = EXP2F(st[2]), p3 = EXP2F(st[3]);
          lacc[mb] += (p0 + p1) + (p2 + p3);
          unsigned a0 = __builtin_bit_cast(unsigned, p0) + 0x8000u;
          unsigned a1 = __builtin_bit_cast(unsigned, p1) + 0x8000u;
          unsigned a2 = __builtin_bit_cast(unsigned, p2) + 0x8000u;
          unsigned a3 = __builtin_bit_cast(unsigned, p3) + 0x8000u;
          uint2 pk;
          pk.x = __builtin_amdgcn_perm(a1, a0, 0x07060302u);
          pk.y = __builtin_amdgcn_perm(a3, a2, 0x07060302u);
          int phys = (4 * kbl + quad) ^ swz;       // 8B slot in 32-key row
          *(uint2*)(myP + (mb * 16 + lr) * 32 + phys * 4) = pk;
        }
      }
      short8 pf[4];
      #pragma unroll
      for (int mb = 0; mb < 4; ++mb) {
        int phys = (2 * quad) ^ swz;               // even slot, pair contiguous (16B)
        pf[mb] = *(const short8*)(myP + (mb * 16 + lr) * 32 + phys * 4);
      }
      #pragma unroll
      for (int db = 0; db < 4; ++db) {
        const short* vr = Vsh + (db * 16 + lr) * 64;
        short8 vf = *(const short8*)(vr + (((kc * 4 + quad) ^ l7) << 3));
        #pragma unroll
        for (int mb = 0; mb < 4; ++mb)
          O[mb][db] = __builtin_amdgcn_mfma_f32_16x16x32_bf16(vf, pf[mb], O[mb][db], 0, 0, 0);
      }
    }
    __syncthreads();   // publishes t+1 buffer (drain overlapped) + retires buffer t
  }

  // ---- merge the two key-halves through LDS ----
  float* Obuf = (float*)smem;                 // 8192 floats (32 KB)
  float* lbuf = (float*)(smem + 32768);       // 512 floats (over P region)
  const int qs = (quad + lr) & 3;             // bank swizzle for Obuf
  if (half == 1) {
    #pragma unroll
    for (int mb = 0; mb < 4; ++mb) {
      #pragma unroll
      for (int db = 0; db < 4; ++db)
        *(f32x4*)(Obuf + ((qg * 4 + mb) * 4 + db) * 256 + lr * 16 + qs * 4) = O[mb][db];
      lbuf[(qg * 4 + mb) * 64 + quad * 16 + lr] = lacc[mb];
    }
  }
  __syncthreads();
  if (half == 0) {
    float beta = *beta_p;
    #pragma unroll
    for (int mb = 0; mb < 4; ++mb) {
      #pragma unroll
      for (int db = 0; db < 4; ++db)
        O[mb][db] += *(const f32x4*)(Obuf + ((qg * 4 + mb) * 4 + db) * 256 + lr * 16 + qs * 4);
      float v = lacc[mb] + lbuf[(qg * 4 + mb) * 64 + quad * 16 + lr];
      v += __shfl_xor(v, 16);
      v += __shfl_xor(v, 32);
      float linv = (1.f - beta) / v;
      #pragma unroll
      for (int db = 0; db < 4; ++db) {
        float4 dv = *(const float4*)(dsV + bh * 64 + db * 16 + quad * 4);
        short4v o;
        o[0] = f2bf(O[mb][db][0] * linv + beta * dv.x);
        o[1] = f2bf(O[mb][db][1] * linv + beta * dv.y);
        o[2] = f2bf(O[mb][db][2] * linv + beta * dv.z);
        o[3] = f2bf(O[mb][db][3] * linv + beta * dv.w);
        *(short4v*)(ctx + (bS + q0 + mb * 16 + lr) * 1024 + h * 64 + db * 16 + quad * 4) = o;
      }
    }
  }
}

// ---------- output projection, BK=64: 64(M) x 128(N) tiles -> 512 blocks ----------
__global__ __launch_bounds__(256, 2) void out_gemm(
    const short* __restrict__ ctx, const short* __restrict__ WoT,
    const float* __restrict__ bo, float* __restrict__ out) {
  __shared__ short As[64 * 64];    // 8 KB
  __shared__ short Bs[128 * 64];   // 16 KB
  const int n0 = blockIdx.x * 128, m0 = blockIdx.y * 64;
  const int tid = threadIdx.x, wave = tid >> 6, lane = tid & 63;
  const int wm = wave >> 1, wn = wave & 1;
  const int lr = lane & 15, quad = lane >> 4;
  const int l7 = lr & 7;
  const int r8 = lane >> 3, cb = lane & 7;
  const int src = (cb ^ r8) << 3;
  f32x4 acc[2][4] = {};
  for (int k0 = 0; k0 < 1024; k0 += 64) {
    __syncthreads();
    #pragma unroll
    for (int jj = 0; jj < 2; ++jj) {
      int j = wave * 2 + jj;
      int row = j * 8 + r8;
      async_load16(ctx + (size_t)(m0 + row) * 1024 + k0 + src, As + j * 512 + lane * 8);
    }
    #pragma unroll
    for (int jj = 0; jj < 4; ++jj) {
      int j = wave * 4 + jj;
      int row = j * 8 + r8;
      async_load16(WoT + (size_t)(n0 + row) * 1024 + k0 + src, Bs + j * 512 + lane * 8);
    }
    __syncthreads();
    #pragma unroll
    for (int c = 0; c < 2; ++c) {
      short8 af[2], bfr[4];
      #pragma unroll
      for (int i = 0; i < 2; ++i) {
        int ra = wm * 32 + i * 16 + lr;
        af[i] = *(const short8*)(As + ra * 64 + (((c * 4 + quad) ^ l7) << 3));
      }
      #pragma unroll
      for (int j = 0; j < 4; ++j) {
        int rb = wn * 64 + j * 16 + lr;
        bfr[j] = *(const short8*)(Bs + rb * 64 + (((c * 4 + quad) ^ l7) << 3));
      }
      #pragma unroll
      for (int i = 0; i < 2; ++i)
        #pragma unroll
        for (int j = 0; j < 4; ++j)
          acc[i][j] = __builtin_amdgcn_mfma_f32_16x16x32_bf16(af[i], bfr[j], acc[i][j], 0, 0, 0);
    }
  }
  #pragma unroll
  for (int i = 0; i < 2; ++i)
    #pragma unroll
    for (int j = 0; j < 4; ++j) {
      int col = n0 + wn * 64 + j * 16 + lr;
      float bb = bo[col];
      int rowb = m0 + wm * 32 + i * 16 + quad * 4;
      #pragma unroll
      for (int r = 0; r < 4; ++r)
        out[(size_t)(rowb + r) * 1024 + col] = acc[i][j][r] + bb;
    }
}

// ---------- launcher: 5 dispatches ----------
extern "C" void kernel_launch(void* const* d_in, const int* in_sizes, int n_in,
                              void* d_out, int out_size, void* d_ws, size_t ws_size,
                              hipStream_t stream) {
  const float* x    = (const float*)d_in[0];
  const float* dsc  = (const float*)d_in[1];
  const float* Wq   = (const float*)d_in[2];
  const float* bq   = (const float*)d_in[3];
  const float* Wk   = (const float*)d_in[4];
  const float* bk   = (const float*)d_in[5];
  const float* Wv   = (const float*)d_in[6];
  const float* bv   = (const float*)d_in[7];
  const float* Wo   = (const float*)d_in[8];
  const float* bo   = (const float*)d_in[9];
  const float* beta = (const float*)d_in[10];

  char* ws = (char*)d_ws;
  const size_t MB = 1u << 20;
  short* xb  = (short*)(ws + 0 * MB);    // 8 MB; reused as ctx after qkv_gemm
  short* WqT = (short*)(ws + 8 * MB);
  short* WkT = (short*)(ws + 10 * MB);
  short* WvT = (short*)(ws + 12 * MB);
  short* WoT = (short*)(ws + 14 * MB);
  short* Qb  = (short*)(ws + 16 * MB);
  short* Kb  = (short*)(ws + 24 * MB);
  short* Vt  = (short*)(ws + 32 * MB);
  float* dsV = (float*)(ws + 40 * MB);   // 8 KB
  short* ctx = xb;

  fused_pre<<<8193, 256, 0, stream>>>(x, xb, Wq, Wk, Wv, Wo, WqT, WkT, WvT, WoT, dsV);
  qkv_gemm<<<dim3(24, 32), 256, 0, stream>>>(xb, WqT, WkT, WvT, bq, bk, bv, Qb, Kb, Vt);
  dsv_kernel<<<dim3(32, 8), 256, 0, stream>>>(Vt, dsc, dsV);
  attn_kernel<<<512, 256, 0, stream>>>(Qb, Kb, Vt, dsV, beta, ctx);
  out_gemm<<<dim3(8, 64), 256, 0, stream>>>(ctx, WoT, bo, (float*)d_out);
}

// Round 9
// 194.673 us; speedup vs baseline: 1.1037x; 1.0341x over previous
//
#include <hip/hip_runtime.h>

// ---------- types / helpers ----------
typedef __attribute__((ext_vector_type(8))) short short8;   // 8 x bf16 (raw)
typedef __attribute__((ext_vector_type(4))) short short4v;  // 4 x bf16 (raw)
typedef __attribute__((ext_vector_type(4))) float f32x4;

#if __has_builtin(__builtin_amdgcn_exp2f)
#define EXP2F(x) __builtin_amdgcn_exp2f(x)
#define QSCALE 0.1803368801111601f   /* log2(e)/8 : logits in log2 domain */
#else
#define EXP2F(x) __expf(x)
#define QSCALE 0.125f                /* logits in ln domain */
#endif

__device__ __forceinline__ short f2bf(float f) {
  unsigned u = __builtin_bit_cast(unsigned, f);
  u += 0x7fffu + ((u >> 16) & 1u);           // RNE
  return (short)(u >> 16);
}
__device__ __forceinline__ float bf2f(short s) {
  unsigned u = ((unsigned)(unsigned short)s) << 16;
  return __builtin_bit_cast(float, u);
}
__device__ __forceinline__ void async_load16(const short* g, short* l) {
  __builtin_amdgcn_global_load_lds(
      (const __attribute__((address_space(1))) unsigned int*)g,
      (__attribute__((address_space(3))) unsigned int*)l, 16, 0, 0);
}

// ---------- fused pre-pass ----------
// blocks 0..4095: convert x; 4096..8191: transpose weights; 8192: zero dsV
__global__ __launch_bounds__(256) void fused_pre(
    const float* __restrict__ x, short* __restrict__ xb,
    const float* __restrict__ W0, const float* __restrict__ W1,
    const float* __restrict__ W2, const float* __restrict__ W3,
    short* __restrict__ T0, short* __restrict__ T1,
    short* __restrict__ T2, short* __restrict__ T3,
    float* __restrict__ dsV) {
  __shared__ float tile[32][33];
  if (blockIdx.x < 4096) {
    int i = (blockIdx.x * 256 + threadIdx.x) * 4;
    float4 v = *(const float4*)(x + i);
    short4v o;
    o[0] = f2bf(v.x); o[1] = f2bf(v.y); o[2] = f2bf(v.z); o[3] = f2bf(v.w);
    *(short4v*)(xb + i) = o;
    return;
  }
  if (blockIdx.x == 8192) {   // zero dsV (2048 floats)
    float4 z = {0.f, 0.f, 0.f, 0.f};
    ((float4*)dsV)[threadIdx.x * 2] = z;
    ((float4*)dsV)[threadIdx.x * 2 + 1] = z;
    return;
  }
  int bid = blockIdx.x - 4096;        // 0..4095
  int z = bid >> 10;                  // weight index
  int by = (bid >> 5) & 31, bx = bid & 31;
  const float* W; short* T;
  switch (z) {
    case 0: W = W0; T = T0; break;
    case 1: W = W1; T = T1; break;
    case 2: W = W2; T = T2; break;
    default: W = W3; T = T3; break;
  }
  int tx = threadIdx.x & 31, ty = threadIdx.x >> 5;
  int c = bx * 32 + tx;
  #pragma unroll
  for (int i = 0; i < 4; ++i) {
    int r = by * 32 + ty + i * 8;
    tile[ty + i * 8][tx] = W[(size_t)r * 1024 + c];
  }
  __syncthreads();
  int k = by * 32 + tx;
  #pragma unroll
  for (int i = 0; i < 4; ++i) {
    int n = bx * 32 + ty + i * 8;
    T[(size_t)n * 1024 + k] = f2bf(tile[tx][ty + i * 8]);
  }
}

// ---------- GEMM core, BK=64: C(128x128) += A @ Bt^T ----------
__device__ __forceinline__ void gemm_core_128_bk64(
    const short* __restrict__ A, const short* __restrict__ Bt,
    int m0, int n0, short* As, short* Bs, f32x4 acc[4][4]) {
  const int tid = threadIdx.x;
  const int wave = tid >> 6, lane = tid & 63;
  const int wm = wave >> 1, wn = wave & 1;
  const int lr = lane & 15, quad = lane >> 4;
  const int l7 = lr & 7;
  const int r8 = lane >> 3, cb = lane & 7;
  const int src = (cb ^ r8) << 3;              // shorts: XOR-swizzled source chunk
  for (int k0 = 0; k0 < 1024; k0 += 64) {
    __syncthreads();
    #pragma unroll
    for (int jj = 0; jj < 4; ++jj) {
      int j = wave * 4 + jj;                   // waveload 0..15, 8 rows each
      int row = j * 8 + r8;
      async_load16(A + (size_t)(m0 + row) * 1024 + k0 + src, As + j * 512 + lane * 8);
      async_load16(Bt + (size_t)(n0 + row) * 1024 + k0 + src, Bs + j * 512 + lane * 8);
    }
    __syncthreads();
    #pragma unroll
    for (int c = 0; c < 2; ++c) {
      short8 af[4], bfr[4];
      #pragma unroll
      for (int i = 0; i < 4; ++i) {
        int ra = wm * 64 + i * 16 + lr;
        af[i] = *(const short8*)(As + ra * 64 + ((((c * 4 + quad) ^ l7)) << 3));
        int rb = wn * 64 + i * 16 + lr;
        bfr[i] = *(const short8*)(Bs + rb * 64 + ((((c * 4 + quad) ^ l7)) << 3));
      }
      #pragma unroll
      for (int i = 0; i < 4; ++i)
        #pragma unroll
        for (int j = 0; j < 4; ++j)
          acc[i][j] = __builtin_amdgcn_mfma_f32_16x16x32_bf16(af[i], bfr[j], acc[i][j], 0, 0, 0);
    }
  }
}

// ---------- fused QKV projection. 3 blocks/CU co-residency ----------
__global__ __launch_bounds__(256, 3) void qkv_gemm(
    const short* __restrict__ xb,
    const short* __restrict__ WqT, const short* __restrict__ WkT, const short* __restrict__ WvT,
    const float* __restrict__ bq, const float* __restrict__ bk, const float* __restrict__ bv,
    short* __restrict__ Qb, short* __restrict__ Kb, short* __restrict__ Vt) {
  __shared__ short As[128 * 64];
  __shared__ short Bs[128 * 64];
  int which = blockIdx.x >> 3;
  int n0 = (blockIdx.x & 7) * 128;
  int m0 = blockIdx.y * 128;
  const short* Bt = (which == 0) ? WqT : (which == 1) ? WkT : WvT;
  const float* bias = (which == 0) ? bq : (which == 1) ? bk : bv;
  f32x4 acc[4][4] = {};
  gemm_core_128_bk64(xb, Bt, m0, n0, As, Bs, acc);
  const int lane = threadIdx.x & 63, wave = threadIdx.x >> 6;
  const int wm = wave >> 1, wn = wave & 1;
  const int lr = lane & 15, quad = lane >> 4;
  if (which < 2) {
    short* Out = (which == 0) ? Qb : Kb;
    const float scale = (which == 0) ? QSCALE : 1.0f;
    #pragma unroll
    for (int i = 0; i < 4; ++i)
      #pragma unroll
      for (int j = 0; j < 4; ++j) {
        int col = n0 + wn * 64 + j * 16 + lr;
        float bb = bias[col];
        int rowb = m0 + wm * 64 + i * 16 + quad * 4;
        #pragma unroll
        for (int r = 0; r < 4; ++r)
          Out[(size_t)(rowb + r) * 1024 + col] = f2bf((acc[i][j][r] + bb) * scale);
      }
  } else {
    #pragma unroll
    for (int i = 0; i < 4; ++i)
      #pragma unroll
      for (int j = 0; j < 4; ++j) {
        int col = n0 + wn * 64 + j * 16 + lr;
        float bb = bias[col];
        int h = col >> 6, d = col & 63;
        int rowb = m0 + wm * 64 + i * 16 + quad * 4;
        int b = rowb >> 11, s = rowb & 2047;
        short4v pk;
        #pragma unroll
        for (int r = 0; r < 4; ++r) pk[r] = f2bf(acc[i][j][r] + bb);
        *(short4v*)(Vt + ((size_t)(b * 16 + h) * 64 + d) * 2048 + s) = pk;
      }
  }
}

// ---------- dsV[bh][d] = sum_s ds[b][s] * V[bh][d][s] ; parallel partials + atomics ----------
__global__ __launch_bounds__(256) void dsv_kernel(const short* __restrict__ Vt,
                                                  const float* __restrict__ ds,
                                                  float* __restrict__ dsV) {
  int bh = blockIdx.x, sc = blockIdx.y;
  int b = bh >> 4;
  int d = threadIdx.x >> 2, part = threadIdx.x & 3;
  const short* vrow = Vt + ((size_t)bh * 64 + d) * 2048 + sc * 256 + part * 64;
  const float* dsrow = ds + (size_t)b * 2048 + sc * 256 + part * 64;
  float acc = 0.f;
  #pragma unroll
  for (int i = 0; i < 64; i += 8) {
    short8 v = *(const short8*)(vrow + i);
    float4 f0 = *(const float4*)(dsrow + i);
    float4 f1 = *(const float4*)(dsrow + i + 4);
    acc += f0.x * bf2f(v[0]) + f0.y * bf2f(v[1]) + f0.z * bf2f(v[2]) + f0.w * bf2f(v[3]);
    acc += f1.x * bf2f(v[4]) + f1.y * bf2f(v[5]) + f1.z * bf2f(v[6]) + f1.w * bf2f(v[7]);
  }
  acc += __shfl_xor(acc, 1);
  acc += __shfl_xor(acc, 2);
  if (part == 0) atomicAdd(dsV + bh * 64 + d, acc);
}

// ---------- attention: dbuf KV, register-resident P (NO P LDS round-trip) ----------
// S^T C-layout (col=q=lane&15, row=key=quad*4+r) IS the 16x16x16 B-operand layout
// (n=lane&15, k=quad*4+j). So PV uses v_mfma_f32_16x16x16_bf16 with pf packed
// in-register from the QK accumulator. LDS = 64KB KV double-buffer only; one
// barrier per 64-key tile (staging of t+1 issued before compute of t).
__global__ __launch_bounds__(256, 2) void attn_kernel(
    const short* __restrict__ Qb, const short* __restrict__ Kb,
    const short* __restrict__ Vt, const float* __restrict__ dsV,
    const float* __restrict__ beta_p, short* __restrict__ ctx) {
  __shared__ short smem[32768];  // 64 KB: 2 buffers x (2 halves x (K 8KB + V 8KB))
  const int tid = threadIdx.x, wave = tid >> 6, lane = tid & 63;
  const int bh = blockIdx.x >> 4, qt = blockIdx.x & 15;
  const int b = bh >> 4, h = bh & 15;
  const size_t bS = (size_t)b * 2048;
  const int lr = lane & 15, quad = lane >> 4;
  const int qg = wave & 1, half = wave >> 1;
  const int q0 = qt * 128 + qg * 64;
  const int l7 = lr & 7;

  const int srow = lane >> 3;
  const int scb = (lane & 7) ^ srow;     // XOR-swizzled source 16B chunk

  // Q B-frags: 64 q-rows x 64 dims (Q prescaled by log2(e)/8)
  short8 qf[4][2];
  #pragma unroll
  for (int mb = 0; mb < 4; ++mb)
    #pragma unroll
    for (int c = 0; c < 2; ++c)
      qf[mb][c] = *(const short8*)(Qb + (bS + q0 + mb * 16 + lr) * 1024 + h * 64 + c * 32 + quad * 8);

  f32x4 O[4][4] = {};
  float lacc[4] = {0.f, 0.f, 0.f, 0.f};

  // prologue: stage tile 0 into buffer 0
  {
    const int k0 = (half * 16) * 64;
    short* Ksh = smem + half * 8192;
    short* Vsh = Ksh + 4096;
    if (qg == 0) {
      #pragma unroll
      for (int c = 0; c < 8; ++c)
        async_load16(Kb + (bS + k0 + c * 8 + srow) * 1024 + h * 64 + scb * 8, Ksh + c * 512);
    } else {
      #pragma unroll
      for (int c = 0; c < 8; ++c)
        async_load16(Vt + ((size_t)bh * 64 + c * 8 + srow) * 2048 + k0 + scb * 8, Vsh + c * 512);
    }
  }
  __syncthreads();

  for (int t = 0; t < 16; ++t) {
    const int cur = t & 1;
    short* Ksh = smem + cur * 16384 + half * 8192;
    short* Vsh = Ksh + 4096;
    // issue next tile's staging (no wait) — drain overlaps the compute below
    if (t < 15) {
      const int k0n = (half * 16 + t + 1) * 64;
      short* Kn = smem + (cur ^ 1) * 16384 + half * 8192;
      short* Vn = Kn + 4096;
      if (qg == 0) {
        #pragma unroll
        for (int c = 0; c < 8; ++c)
          async_load16(Kb + (bS + k0n + c * 8 + srow) * 1024 + h * 64 + scb * 8, Kn + c * 512);
      } else {
        #pragma unroll
        for (int c = 0; c < 8; ++c)
          async_load16(Vt + ((size_t)bh * 64 + c * 8 + srow) * 2048 + k0n + scb * 8, Vn + c * 512);
      }
    }
    // compute tile t: 4 groups of 16 keys
    #pragma unroll
    for (int kb = 0; kb < 4; ++kb) {
      // K A-frags for S^T = K @ Q^T (16x16x32, k=dims)
      const short* kr = Ksh + (kb * 16 + lr) * 64;
      short8 kf0 = *(const short8*)(kr + ((quad ^ l7) << 3));
      short8 kf1 = *(const short8*)(kr + (((4 + quad) ^ l7) << 3));
      short4v pf[4];
      #pragma unroll
      for (int mb = 0; mb < 4; ++mb) {
        f32x4 st = {0.f, 0.f, 0.f, 0.f};
        st = __builtin_amdgcn_mfma_f32_16x16x32_bf16(kf0, qf[mb][0], st, 0, 0, 0);
        st = __builtin_amdgcn_mfma_f32_16x16x32_bf16(kf1, qf[mb][1], st, 0, 0, 0);
        float p0 = EXP2F(st[0]), p1 = EXP2F(st[1]);
        float p2 = EXP2F(st[2]), p3 = EXP2F(st[3]);
        lacc[mb] += (p0 + p1) + (p2 + p3);
        // pack P into the 16x16x16 B-operand fragment (round-half-up bf16)
        unsigned a0 = __builtin_bit_cast(unsigned, p0) + 0x8000u;
        unsigned a1 = __builtin_bit_cast(unsigned, p1) + 0x8000u;
        unsigned a2 = __builtin_bit_cast(unsigned, p2) + 0x8000u;
        unsigned a3 = __builtin_bit_cast(unsigned, p3) + 0x8000u;
        uint2 pk;
        pk.x = __builtin_amdgcn_perm(a1, a0, 0x07060302u);
        pk.y = __builtin_amdgcn_perm(a3, a2, 0x07060302u);
        pf[mb] = __builtin_bit_cast(short4v, pk);
      }
      // O^T += V^T @ P^T via 16x16x16 (k = 16 keys of this kb group)
      #pragma unroll
      for (int db = 0; db < 4; ++db) {
        int vrow = db * 16 + lr;
        int chunk = (2 * kb + (quad >> 1)) ^ l7;
        short4v vf = *(const short4v*)(Vsh + vrow * 64 + chunk * 8 + (quad & 1) * 4);
        #pragma unroll
        for (int mb = 0; mb < 4; ++mb)
          O[mb][db] = __builtin_amdgcn_mfma_f32_16x16x16bf16_1k(vf, pf[mb], O[mb][db], 0, 0, 0);
      }
    }
    __syncthreads();   // publishes t+1 buffer (drain overlapped) + retires buffer t
  }

  // ---- merge the two key-halves through LDS (reuses KV region; loop barrier passed) ----
  float* Obuf = (float*)smem;                 // 8192 floats (32 KB)
  float* lbuf = ((float*)smem) + 8192;        // 512 floats
  const int qs = (quad + lr) & 3;             // bank swizzle for Obuf
  if (half == 1) {
    #pragma unroll
    for (int mb = 0; mb < 4; ++mb) {
      #pragma unroll
      for (int db = 0; db < 4; ++db)
        *(f32x4*)(Obuf + ((qg * 4 + mb) * 4 + db) * 256 + lr * 16 + qs * 4) = O[mb][db];
      lbuf[(qg * 4 + mb) * 64 + quad * 16 + lr] = lacc[mb];
    }
  }
  __syncthreads();
  if (half == 0) {
    float beta = *beta_p;
    #pragma unroll
    for (int mb = 0; mb < 4; ++mb) {
      #pragma unroll
      for (int db = 0; db < 4; ++db)
        O[mb][db] += *(const f32x4*)(Obuf + ((qg * 4 + mb) * 4 + db) * 256 + lr * 16 + qs * 4);
      float v = lacc[mb] + lbuf[(qg * 4 + mb) * 64 + quad * 16 + lr];
      v += __shfl_xor(v, 16);
      v += __shfl_xor(v, 32);
      float linv = (1.f - beta) / v;
      #pragma unroll
      for (int db = 0; db < 4; ++db) {
        float4 dv = *(const float4*)(dsV + bh * 64 + db * 16 + quad * 4);
        short4v o;
        o[0] = f2bf(O[mb][db][0] * linv + beta * dv.x);
        o[1] = f2bf(O[mb][db][1] * linv + beta * dv.y);
        o[2] = f2bf(O[mb][db][2] * linv + beta * dv.z);
        o[3] = f2bf(O[mb][db][3] * linv + beta * dv.w);
        *(short4v*)(ctx + (bS + q0 + mb * 16 + lr) * 1024 + h * 64 + db * 16 + quad * 4) = o;
      }
    }
  }
}

// ---------- output projection, BK=64: 64(M) x 128(N) tiles -> 512 blocks ----------
__global__ __launch_bounds__(256, 2) void out_gemm(
    const short* __restrict__ ctx, const short* __restrict__ WoT,
    const float* __restrict__ bo, float* __restrict__ out) {
  __shared__ short As[64 * 64];    // 8 KB
  __shared__ short Bs[128 * 64];   // 16 KB
  const int n0 = blockIdx.x * 128, m0 = blockIdx.y * 64;
  const int tid = threadIdx.x, wave = tid >> 6, lane = tid & 63;
  const int wm = wave >> 1, wn = wave & 1;
  const int lr = lane & 15, quad = lane >> 4;
  const int l7 = lr & 7;
  const int r8 = lane >> 3, cb = lane & 7;
  const int src = (cb ^ r8) << 3;
  f32x4 acc[2][4] = {};
  for (int k0 = 0; k0 < 1024; k0 += 64) {
    __syncthreads();
    #pragma unroll
    for (int jj = 0; jj < 2; ++jj) {
      int j = wave * 2 + jj;
      int row = j * 8 + r8;
      async_load16(ctx + (size_t)(m0 + row) * 1024 + k0 + src, As + j * 512 + lane * 8);
    }
    #pragma unroll
    for (int jj = 0; jj < 4; ++jj) {
      int j = wave * 4 + jj;
      int row = j * 8 + r8;
      async_load16(WoT + (size_t)(n0 + row) * 1024 + k0 + src, Bs + j * 512 + lane * 8);
    }
    __syncthreads();
    #pragma unroll
    for (int c = 0; c < 2; ++c) {
      short8 af[2], bfr[4];
      #pragma unroll
      for (int i = 0; i < 2; ++i) {
        int ra = wm * 32 + i * 16 + lr;
        af[i] = *(const short8*)(As + ra * 64 + (((c * 4 + quad) ^ l7) << 3));
      }
      #pragma unroll
      for (int j = 0; j < 4; ++j) {
        int rb = wn * 64 + j * 16 + lr;
        bfr[j] = *(const short8*)(Bs + rb * 64 + (((c * 4 + quad) ^ l7) << 3));
      }
      #pragma unroll
      for (int i = 0; i < 2; ++i)
        #pragma unroll
        for (int j = 0; j < 4; ++j)
          acc[i][j] = __builtin_amdgcn_mfma_f32_16x16x32_bf16(af[i], bfr[j], acc[i][j], 0, 0, 0);
    }
  }
  #pragma unroll
  for (int i = 0; i < 2; ++i)
    #pragma unroll
    for (int j = 0; j < 4; ++j) {
      int col = n0 + wn * 64 + j * 16 + lr;
      float bb = bo[col];
      int rowb = m0 + wm * 32 + i * 16 + quad * 4;
      #pragma unroll
      for (int r = 0; r < 4; ++r)
        out[(size_t)(rowb + r) * 1024 + col] = acc[i][j][r] + bb;
    }
}

// ---------- launcher: 5 dispatches ----------
extern "C" void kernel_launch(void* const* d_in, const int* in_sizes, int n_in,
                              void* d_out, int out_size, void* d_ws, size_t ws_size,
                              hipStream_t stream) {
  const float* x    = (const float*)d_in[0];
  const float* dsc  = (const float*)d_in[1];
  const float* Wq   = (const float*)d_in[2];
  const float* bq   = (const float*)d_in[3];
  const float* Wk   = (const float*)d_in[4];
  const float* bk   = (const float*)d_in[5];
  const float* Wv   = (const float*)d_in[6];
  const float* bv   = (const float*)d_in[7];
  const float* Wo   = (const float*)d_in[8];
  const float* bo   = (const float*)d_in[9];
  const float* beta = (const float*)d_in[10];

  char* ws = (char*)d_ws;
  const size_t MB = 1u << 20;
  short* xb  = (short*)(ws + 0 * MB);    // 8 MB; reused as ctx after qkv_gemm
  short* WqT = (short*)(ws + 8 * MB);
  short* WkT = (short*)(ws + 10 * MB);
  short* WvT = (short*)(ws + 12 * MB);
  short* WoT = (short*)(ws + 14 * MB);
  short* Qb  = (short*)(ws + 16 * MB);
  short* Kb  = (short*)(ws + 24 * MB);
  short* Vt  = (short*)(ws + 32 * MB);
  float* dsV = (float*)(ws + 40 * MB);   // 8 KB
  short* ctx = xb;

  fused_pre<<<8193, 256, 0, stream>>>(x, xb, Wq, Wk, Wv, Wo, WqT, WkT, WvT, WoT, dsV);
  qkv_gemm<<<dim3(24, 32), 256, 0, stream>>>(xb, WqT, WkT, WvT, bq, bk, bv, Qb, Kb, Vt);
  dsv_kernel<<<dim3(32, 8), 256, 0, stream>>>(Vt, dsc, dsV);
  attn_kernel<<<512, 256, 0, stream>>>(Qb, Kb, Vt, dsV, beta, ctx);
  out_gemm<<<dim3(8, 64), 256, 0, stream>>>(ctx, WoT, bo, (float*)d_out);
}